// Round 1
// baseline (140.203 us; speedup 1.0000x reference)
//
#include <hip/hip_runtime.h>

typedef __attribute__((ext_vector_type(4))) float v4f;
typedef __attribute__((ext_vector_type(8))) short short8;
typedef unsigned short u16;
typedef __attribute__((ext_vector_type(4))) unsigned short u16x4;

#define CDIM 256
#define NB 8
#define NN 4096
#define MM 4096

static __device__ __forceinline__ u16 f2bf(float f) {
  unsigned u = __float_as_uint(f);
  u = (u + 0x7fffu + ((u >> 16) & 1u)) >> 16;  // RNE
  return (u16)u;
}

// ---------------- K0: inv-norms of key rows ----------------
__global__ __launch_bounds__(256) void knorm_kernel(const float* __restrict__ key,
                                                    float* __restrict__ sk) {
  int t = threadIdx.x;
  int lane = t & 63;
  int r = blockIdx.x * 4 + (t >> 6);
  const v4f x = *(const v4f*)(key + (size_t)r * CDIM + lane * 4);
  float ss = x[0]*x[0] + x[1]*x[1] + x[2]*x[2] + x[3]*x[3];
  #pragma unroll
  for (int m = 1; m < 64; m <<= 1) ss += __shfl_xor(ss, m);
  if (lane == 0) sk[r] = 1.0f / fmaxf(sqrtf(ss), 1e-12f);
}

// ---------------- K1: kv partials = (k*s)^T @ v, split-K ----------------
__global__ __launch_bounds__(512, 2) void kv_kernel(const float* __restrict__ key,
                                                    const float* __restrict__ value,
                                                    const float* __restrict__ sk,
                                                    u16* __restrict__ partial, int KC) {
  __shared__ __align__(16) u16 knT[256 * 64];  // [c][m] bf16, XOR-swizzled
  __shared__ __align__(16) u16 vT[256 * 64];   // [d][m] bf16, XOR-swizzled
  int t = threadIdx.x;
  int b = blockIdx.y, s = blockIdx.x;
  int w = t >> 6, lane = t & 63, lo = lane & 15, hi = lane >> 4;
  int cstage = t & 255, wq = t >> 8;

  v4f acc[2][16];
  #pragma unroll
  for (int i = 0; i < 2; i++)
    #pragma unroll
    for (int d = 0; d < 16; d++) acc[i][d] = (v4f){0.f, 0.f, 0.f, 0.f};

  int nsc = KC >> 6;
  for (int sc = 0; sc < nsc; ++sc) {
    int mbase = s * KC + sc * 64;
    // stage 64 m-rows: transpose + normalize(k) + bf16
    #pragma unroll
    for (int it = 0; it < 8; ++it) {
      int ml0 = it * 8 + wq * 4;
      int gr = b * MM + mbase + ml0;
      size_t grow = (size_t)gr * CDIM + cstage;
      float k0 = key[grow], k1 = key[grow + CDIM], k2 = key[grow + 2 * CDIM], k3 = key[grow + 3 * CDIM];
      float s0 = sk[gr], s1 = sk[gr + 1], s2 = sk[gr + 2], s3 = sk[gr + 3];
      u16x4 kn = { f2bf(k0 * s0), f2bf(k1 * s1), f2bf(k2 * s2), f2bf(k3 * s3) };
      int idx = (cstage * 64 + ml0) ^ ((cstage & 7) << 3);
      *(u16x4*)&knT[idx] = kn;
      float v0 = value[grow], v1 = value[grow + CDIM], v2 = value[grow + 2 * CDIM], v3 = value[grow + 3 * CDIM];
      u16x4 vn = { f2bf(v0), f2bf(v1), f2bf(v2), f2bf(v3) };
      *(u16x4*)&vT[idx] = vn;
    }
    __syncthreads();
    // MFMA: wave w owns c-tiles {2w, 2w+1} x all 16 d-tiles
    #pragma unroll
    for (int kk = 0; kk < 64; kk += 32) {
      int acol = kk + hi * 8;
      int r0 = w * 32 + lo, r1 = w * 32 + 16 + lo;
      short8 a0 = *(const short8*)&knT[(r0 * 64 + acol) ^ ((r0 & 7) << 3)];
      short8 a1 = *(const short8*)&knT[(r1 * 64 + acol) ^ ((r1 & 7) << 3)];
      #pragma unroll
      for (int dt = 0; dt < 16; ++dt) {
        int drow = dt * 16 + lo;
        short8 bb = *(const short8*)&vT[(drow * 64 + acol) ^ ((drow & 7) << 3)];
        acc[0][dt] = __builtin_amdgcn_mfma_f32_16x16x32_bf16(a0, bb, acc[0][dt], 0, 0, 0);
        acc[1][dt] = __builtin_amdgcn_mfma_f32_16x16x32_bf16(a1, bb, acc[1][dt], 0, 0, 0);
      }
    }
    __syncthreads();
  }
  // epilogue: bf16 partial [s][b][256 c][256 d]
  size_t base = ((size_t)(s * NB + b)) << 16;
  #pragma unroll
  for (int i = 0; i < 2; i++) {
    int c0 = w * 32 + i * 16 + hi * 4;
    #pragma unroll
    for (int dt = 0; dt < 16; ++dt) {
      int d = dt * 16 + lo;
      #pragma unroll
      for (int r = 0; r < 4; r++)
        partial[base + (size_t)(c0 + r) * 256 + d] = f2bf(acc[i][dt][r]);
    }
  }
}

// ---------------- K2: reduce partials, scale 1/N, write kvT[d][c] bf16 ----------------
__global__ __launch_bounds__(256) void red_kernel(const u16* __restrict__ partial,
                                                  u16* __restrict__ kvT, int splits) {
  __shared__ float T[64 * 65];
  int t = threadIdx.x;
  int b = blockIdx.y;
  int c0 = (blockIdx.x & 3) * 64, d0 = (blockIdx.x >> 2) * 64;
  const float inv = 1.0f / 4096.0f;
  for (int it = 0; it < 8; ++it) {
    int cl = it * 8 + (t >> 5);
    int dd = (t & 31) * 2;
    float s0 = 0.f, s1 = 0.f;
    for (int s = 0; s < splits; ++s) {
      unsigned u = *(const unsigned*)&partial[(((size_t)(s * NB + b)) << 16) + (size_t)(c0 + cl) * 256 + d0 + dd];
      s0 += __uint_as_float((u & 0xffffu) << 16);
      s1 += __uint_as_float(u & 0xffff0000u);
    }
    T[cl * 65 + dd] = s0 * inv;
    T[cl * 65 + dd + 1] = s1 * inv;
  }
  __syncthreads();
  for (int it = 0; it < 8; ++it) {
    int dl = it * 8 + (t >> 5);
    int cc = (t & 31) * 2;
    unsigned u = (unsigned)f2bf(T[cc * 65 + dl]) | ((unsigned)f2bf(T[(cc + 1) * 65 + dl]) << 16);
    *(unsigned*)&kvT[(size_t)(b * 256 + d0 + dl) * 256 + c0 + cc] = u;
  }
}

// ---------------- K3: out = normalize(q) @ kv  (1/N already folded in kvT) ----------------
__global__ __launch_bounds__(256, 2) void ctx_kernel(const float* __restrict__ query,
                                                     const u16* __restrict__ kvT,
                                                     float* __restrict__ out) {
  __shared__ __align__(16) u16 qn[64 * 256];  // [n][c] bf16, XOR-swizzled
  int t = threadIdx.x;
  int b = blockIdx.y;
  int n0 = blockIdx.x * 64;
  int lane = t & 63, w = t >> 6, lo = lane & 15, hi = lane >> 4;
  // stage + inline normalize (one row per wave per iter)
  #pragma unroll 4
  for (int it = 0; it < 16; ++it) {
    int nl = it * 4 + w;
    const v4f x = *(const v4f*)(query + (size_t)(b * NN + n0 + nl) * CDIM + lane * 4);
    float ss = x[0]*x[0] + x[1]*x[1] + x[2]*x[2] + x[3]*x[3];
    #pragma unroll
    for (int m2 = 1; m2 < 64; m2 <<= 1) ss += __shfl_xor(ss, m2);
    float sc = 1.0f / fmaxf(sqrtf(ss), 1e-12f);
    u16x4 qb = { f2bf(x[0] * sc), f2bf(x[1] * sc), f2bf(x[2] * sc), f2bf(x[3] * sc) };
    int idx = (nl * 256 + lane * 4) ^ ((nl & 7) << 3);
    *(u16x4*)&qn[idx] = qb;
  }
  __syncthreads();
  v4f acc[16];
  #pragma unroll
  for (int d = 0; d < 16; ++d) acc[d] = (v4f){0.f, 0.f, 0.f, 0.f};
  const u16* kvb = kvT + ((size_t)b << 16);
  for (int kc = 0; kc < 256; kc += 32) {
    int arow = 16 * w + lo;
    short8 a = *(const short8*)&qn[(arow * 256 + kc + 8 * hi) ^ ((arow & 7) << 3)];
    #pragma unroll
    for (int dt = 0; dt < 16; ++dt) {
      short8 bb = *(const short8*)&kvb[(size_t)(dt * 16 + lo) * 256 + kc + 8 * hi];
      acc[dt] = __builtin_amdgcn_mfma_f32_16x16x32_bf16(a, bb, acc[dt], 0, 0, 0);
    }
  }
  #pragma unroll
  for (int dt = 0; dt < 16; ++dt) {
    #pragma unroll
    for (int r = 0; r < 4; ++r)
      out[(size_t)(b * NN + n0 + 16 * w + 4 * hi + r) * CDIM + dt * 16 + lo] = acc[dt][r];
  }
}

extern "C" void kernel_launch(void* const* d_in, const int* in_sizes, int n_in,
                              void* d_out, int out_size, void* d_ws, size_t ws_size,
                              hipStream_t stream) {
  const float* q = (const float*)d_in[0];
  const float* k = (const float*)d_in[1];
  const float* v = (const float*)d_in[2];
  float* out = (float*)d_out;

  // ws layout: [s_k: 32768 f32][partial: splits*8*256*256 bf16][kvT: 8*256*256 bf16]
  int splits = 32;
  while (splits > 2) {
    size_t need = 131072ull + ((size_t)splits + 1ull) * 1048576ull;
    if (need <= ws_size) break;
    splits >>= 1;
  }
  float* s_k = (float*)d_ws;
  u16* partial = (u16*)((char*)d_ws + 131072);
  u16* kvT = (u16*)((char*)d_ws + 131072 + (size_t)splits * 1048576ull);

  knorm_kernel<<<dim3(8192), dim3(256), 0, stream>>>(k, s_k);
  kv_kernel<<<dim3(splits, NB), dim3(512), 0, stream>>>(k, v, s_k, partial, MM / splits);
  red_kernel<<<dim3(16, NB), dim3(256), 0, stream>>>(partial, kvT, splits);
  ctx_kernel<<<dim3(64, NB), dim3(256), 0, stream>>>(q, kvT, out);
}

// Round 2
// 87.416 us; speedup vs baseline: 1.6039x; 1.6039x over previous
//
#include <hip/hip_runtime.h>

typedef __attribute__((ext_vector_type(4))) float v4f;
typedef __attribute__((ext_vector_type(8))) short short8;
typedef unsigned short u16;
typedef __attribute__((ext_vector_type(4))) unsigned short u16x4;
typedef __attribute__((ext_vector_type(8))) unsigned short u16x8;

#define CDIM 256
#define NB 8
#define NN 4096
#define MM 4096

static __device__ __forceinline__ u16 f2bf(float f) {
  unsigned u = __float_as_uint(f);
  u = (u + 0x7fffu + ((u >> 16) & 1u)) >> 16;  // RNE
  return (u16)u;
}
static __device__ __forceinline__ float bf2f(u16 h) {
  return __uint_as_float(((unsigned)h) << 16);
}

// ---------------- K0: inv-norms of key rows ----------------
__global__ __launch_bounds__(256) void knorm_kernel(const float* __restrict__ key,
                                                    float* __restrict__ sk) {
  int t = threadIdx.x;
  int lane = t & 63;
  int r = blockIdx.x * 4 + (t >> 6);
  const v4f x = *(const v4f*)(key + (size_t)r * CDIM + lane * 4);
  float ss = x[0]*x[0] + x[1]*x[1] + x[2]*x[2] + x[3]*x[3];
  #pragma unroll
  for (int m = 1; m < 64; m <<= 1) ss += __shfl_xor(ss, m);
  if (lane == 0) sk[r] = 1.0f / fmaxf(sqrtf(ss), 1e-12f);
}

// ---------------- K1: kv partials = v^T @ (k*s), split-K, output [d][c] ----------------
__global__ __launch_bounds__(512, 2) void kv_kernel(const float* __restrict__ key,
                                                    const float* __restrict__ value,
                                                    const float* __restrict__ sk,
                                                    u16* __restrict__ partial, int KC) {
  __shared__ __align__(16) u16 knT[256 * 64];  // [c][m] bf16, XOR-swizzled
  __shared__ __align__(16) u16 vT[256 * 64];   // [d][m] bf16, XOR-swizzled
  int t = threadIdx.x;
  int b = blockIdx.y, s = blockIdx.x;
  int w = t >> 6, lane = t & 63, lo = lane & 15, hi = lane >> 4;
  int cstage = t & 255, wq = t >> 8;

  v4f acc[2][16];
  #pragma unroll
  for (int i = 0; i < 2; i++)
    #pragma unroll
    for (int d = 0; d < 16; d++) acc[i][d] = (v4f){0.f, 0.f, 0.f, 0.f};

  int nsc = KC >> 6;
  for (int sc = 0; sc < nsc; ++sc) {
    int mbase = s * KC + sc * 64;
    // stage 64 m-rows: transpose + normalize(k) + bf16
    #pragma unroll
    for (int it = 0; it < 8; ++it) {
      int ml0 = it * 8 + wq * 4;
      int gr = b * MM + mbase + ml0;
      size_t grow = (size_t)gr * CDIM + cstage;
      float k0 = key[grow], k1 = key[grow + CDIM], k2 = key[grow + 2 * CDIM], k3 = key[grow + 3 * CDIM];
      float s0 = sk[gr], s1 = sk[gr + 1], s2 = sk[gr + 2], s3 = sk[gr + 3];
      u16x4 kn = { f2bf(k0 * s0), f2bf(k1 * s1), f2bf(k2 * s2), f2bf(k3 * s3) };
      int idx = (cstage * 64 + ml0) ^ ((cstage & 7) << 3);
      *(u16x4*)&knT[idx] = kn;
      float v0 = value[grow], v1 = value[grow + CDIM], v2 = value[grow + 2 * CDIM], v3 = value[grow + 3 * CDIM];
      u16x4 vn = { f2bf(v0), f2bf(v1), f2bf(v2), f2bf(v3) };
      *(u16x4*)&vT[idx] = vn;
    }
    __syncthreads();
    // MFMA (operands swapped => output rows=d, cols=c):
    // wave w owns c-tiles {2w, 2w+1} x all 16 d-tiles
    #pragma unroll
    for (int kk = 0; kk < 64; kk += 32) {
      int acol = kk + hi * 8;
      int r0 = w * 32 + lo, r1 = w * 32 + 16 + lo;
      short8 a0 = *(const short8*)&knT[(r0 * 64 + acol) ^ ((r0 & 7) << 3)];
      short8 a1 = *(const short8*)&knT[(r1 * 64 + acol) ^ ((r1 & 7) << 3)];
      #pragma unroll
      for (int dt = 0; dt < 16; ++dt) {
        int drow = dt * 16 + lo;
        short8 bb = *(const short8*)&vT[(drow * 64 + acol) ^ ((drow & 7) << 3)];
        acc[0][dt] = __builtin_amdgcn_mfma_f32_16x16x32_bf16(bb, a0, acc[0][dt], 0, 0, 0);
        acc[1][dt] = __builtin_amdgcn_mfma_f32_16x16x32_bf16(bb, a1, acc[1][dt], 0, 0, 0);
      }
    }
    __syncthreads();
  }
  // epilogue: bf16 partial [s][b][256 d][256 c]
  size_t base = ((size_t)(s * NB + b)) << 16;
  #pragma unroll
  for (int i = 0; i < 2; i++) {
    int cc = w * 32 + i * 16 + lo;
    #pragma unroll
    for (int dt = 0; dt < 16; ++dt) {
      int dd = dt * 16 + hi * 4;
      #pragma unroll
      for (int r = 0; r < 4; r++)
        partial[base + (size_t)(dd + r) * 256 + cc] = f2bf(acc[i][dt][r]);
    }
  }
}

// ---------------- K2: elementwise reduce partials, scale 1/N, write kvT[d][c] bf16 ----------------
__global__ __launch_bounds__(256) void red_kernel(const u16* __restrict__ partial,
                                                  u16* __restrict__ kvT, int splits) {
  int j = blockIdx.x * 256 + threadIdx.x;   // 0..65535
  int b = j >> 13;
  int e0 = (j & 8191) * 8;
  size_t off = ((size_t)b << 16) + e0;
  const float inv = 1.0f / 4096.0f;
  float sum[8] = {0.f, 0.f, 0.f, 0.f, 0.f, 0.f, 0.f, 0.f};
  for (int s = 0; s < splits; ++s) {
    u16x8 p = *(const u16x8*)&partial[(((size_t)s * NB) << 16) + off];
    #pragma unroll
    for (int x = 0; x < 8; ++x) sum[x] += bf2f(p[x]);
  }
  u16x8 o;
  #pragma unroll
  for (int x = 0; x < 8; ++x) o[x] = f2bf(sum[x] * inv);
  *(u16x8*)&kvT[off] = o;
}

// ---------------- K3: out = normalize(q) @ kv  (1/N already folded in kvT) ----------------
__global__ __launch_bounds__(256, 2) void ctx_kernel(const float* __restrict__ query,
                                                     const u16* __restrict__ kvT,
                                                     float* __restrict__ out) {
  __shared__ __align__(16) u16 qn[64 * 256];  // [n][c] bf16, XOR-swizzled
  int t = threadIdx.x;
  int b = blockIdx.y;
  int n0 = blockIdx.x * 64;
  int lane = t & 63, w = t >> 6, lo = lane & 15, hi = lane >> 4;
  // stage + inline normalize (one row per wave per iter)
  #pragma unroll 4
  for (int it = 0; it < 16; ++it) {
    int nl = it * 4 + w;
    const v4f x = *(const v4f*)(query + (size_t)(b * NN + n0 + nl) * CDIM + lane * 4);
    float ss = x[0]*x[0] + x[1]*x[1] + x[2]*x[2] + x[3]*x[3];
    #pragma unroll
    for (int m2 = 1; m2 < 64; m2 <<= 1) ss += __shfl_xor(ss, m2);
    float sc = 1.0f / fmaxf(sqrtf(ss), 1e-12f);
    u16x4 qb = { f2bf(x[0] * sc), f2bf(x[1] * sc), f2bf(x[2] * sc), f2bf(x[3] * sc) };
    int idx = (nl * 256 + lane * 4) ^ ((nl & 7) << 3);
    *(u16x4*)&qn[idx] = qb;
  }
  __syncthreads();
  v4f acc[16];
  #pragma unroll
  for (int d = 0; d < 16; ++d) acc[d] = (v4f){0.f, 0.f, 0.f, 0.f};
  const u16* kvb = kvT + ((size_t)b << 16);
  for (int kc = 0; kc < 256; kc += 32) {
    int arow = 16 * w + lo;
    short8 a = *(const short8*)&qn[(arow * 256 + kc + 8 * hi) ^ ((arow & 7) << 3)];
    #pragma unroll
    for (int dt = 0; dt < 16; ++dt) {
      short8 bb = *(const short8*)&kvb[(size_t)(dt * 16 + lo) * 256 + kc + 8 * hi];
      acc[dt] = __builtin_amdgcn_mfma_f32_16x16x32_bf16(a, bb, acc[dt], 0, 0, 0);
    }
  }
  #pragma unroll
  for (int dt = 0; dt < 16; ++dt) {
    #pragma unroll
    for (int r = 0; r < 4; ++r)
      out[(size_t)(b * NN + n0 + 16 * w + 4 * hi + r) * CDIM + dt * 16 + lo] = acc[dt][r];
  }
}

extern "C" void kernel_launch(void* const* d_in, const int* in_sizes, int n_in,
                              void* d_out, int out_size, void* d_ws, size_t ws_size,
                              hipStream_t stream) {
  const float* q = (const float*)d_in[0];
  const float* k = (const float*)d_in[1];
  const float* v = (const float*)d_in[2];
  float* out = (float*)d_out;

  // ws layout: [s_k: 32768 f32][partial: splits*8*256*256 bf16][kvT: 8*256*256 bf16]
  int splits = 32;
  while (splits > 2) {
    size_t need = 131072ull + ((size_t)splits + 1ull) * 1048576ull;
    if (need <= ws_size) break;
    splits >>= 1;
  }
  float* s_k = (float*)d_ws;
  u16* partial = (u16*)((char*)d_ws + 131072);
  u16* kvT = (u16*)((char*)d_ws + 131072 + (size_t)splits * 1048576ull);

  knorm_kernel<<<dim3(8192), dim3(256), 0, stream>>>(k, s_k);
  kv_kernel<<<dim3(splits, NB), dim3(512), 0, stream>>>(k, v, s_k, partial, MM / splits);
  red_kernel<<<dim3(256), dim3(256), 0, stream>>>(partial, kvT, splits);
  ctx_kernel<<<dim3(64, NB), dim3(256), 0, stream>>>(q, kvT, out);
}

// Round 3
// 66.462 us; speedup vs baseline: 2.1095x; 1.3153x over previous
//
#include <hip/hip_runtime.h>

typedef __attribute__((ext_vector_type(4))) float v4f;
typedef __attribute__((ext_vector_type(8))) short short8;
typedef unsigned short u16;
typedef __attribute__((ext_vector_type(4))) unsigned short u16x4;
typedef __attribute__((ext_vector_type(8))) unsigned short u16x8;

#define CDIM 256
#define NB 8
#define NN 4096
#define MM 4096

static __device__ __forceinline__ u16 f2bf(float f) {
  unsigned u = __float_as_uint(f);
  u = (u + 0x7fffu + ((u >> 16) & 1u)) >> 16;  // RNE
  return (u16)u;
}
static __device__ __forceinline__ float bf2f(u16 h) {
  return __uint_as_float(((unsigned)h) << 16);
}

// ---------------- K0: inv-norms of key rows ----------------
__global__ __launch_bounds__(256) void knorm_kernel(const float* __restrict__ key,
                                                    float* __restrict__ sk) {
  int t = threadIdx.x;
  int lane = t & 63;
  int r = blockIdx.x * 4 + (t >> 6);
  const v4f x = *(const v4f*)(key + (size_t)r * CDIM + lane * 4);
  float ss = x[0]*x[0] + x[1]*x[1] + x[2]*x[2] + x[3]*x[3];
  #pragma unroll
  for (int m = 1; m < 64; m <<= 1) ss += __shfl_xor(ss, m);
  if (lane == 0) sk[r] = 1.0f / fmaxf(sqrtf(ss), 1e-12f);
}

// ---------------- K1: kv partials = v^T @ (k*s), split-K, output [d][c] ----------------
__global__ __launch_bounds__(512, 2) void kv_kernel(const float* __restrict__ key,
                                                    const float* __restrict__ value,
                                                    const float* __restrict__ sk,
                                                    u16* __restrict__ partial, int KC) {
  __shared__ __align__(16) u16 knT[256 * 64];  // [c][m] bf16, XOR-swizzled
  __shared__ __align__(16) u16 vT[256 * 64];   // [d][m] bf16, XOR-swizzled
  int t = threadIdx.x;
  int b = blockIdx.y, s = blockIdx.x;
  int w = t >> 6, lane = t & 63, lo = lane & 15, hi = lane >> 4;
  int cstage = t & 255, wq = t >> 8;

  v4f acc[2][16];
  #pragma unroll
  for (int i = 0; i < 2; i++)
    #pragma unroll
    for (int d = 0; d < 16; d++) acc[i][d] = (v4f){0.f, 0.f, 0.f, 0.f};

  int nsc = KC >> 6;
  for (int sc = 0; sc < nsc; ++sc) {
    int mbase = s * KC + sc * 64;
    // stage 64 m-rows: transpose + normalize(k) + bf16
    #pragma unroll
    for (int it = 0; it < 8; ++it) {
      int ml0 = it * 8 + wq * 4;
      int gr = b * MM + mbase + ml0;
      size_t grow = (size_t)gr * CDIM + cstage;
      float k0 = key[grow], k1 = key[grow + CDIM], k2 = key[grow + 2 * CDIM], k3 = key[grow + 3 * CDIM];
      float s0 = sk[gr], s1 = sk[gr + 1], s2 = sk[gr + 2], s3 = sk[gr + 3];
      u16x4 kn = { f2bf(k0 * s0), f2bf(k1 * s1), f2bf(k2 * s2), f2bf(k3 * s3) };
      int idx = (cstage * 64 + ml0) ^ ((cstage & 7) << 3);
      *(u16x4*)&knT[idx] = kn;
      float v0 = value[grow], v1 = value[grow + CDIM], v2 = value[grow + 2 * CDIM], v3 = value[grow + 3 * CDIM];
      u16x4 vn = { f2bf(v0), f2bf(v1), f2bf(v2), f2bf(v3) };
      *(u16x4*)&vT[idx] = vn;
    }
    __syncthreads();
    // MFMA (operands swapped => output rows=d, cols=c):
    // wave w owns c-tiles {2w, 2w+1} x all 16 d-tiles
    #pragma unroll
    for (int kk = 0; kk < 64; kk += 32) {
      int acol = kk + hi * 8;
      int r0 = w * 32 + lo, r1 = w * 32 + 16 + lo;
      short8 a0 = *(const short8*)&knT[(r0 * 64 + acol) ^ ((r0 & 7) << 3)];
      short8 a1 = *(const short8*)&knT[(r1 * 64 + acol) ^ ((r1 & 7) << 3)];
      #pragma unroll
      for (int dt = 0; dt < 16; ++dt) {
        int drow = dt * 16 + lo;
        short8 bb = *(const short8*)&vT[(drow * 64 + acol) ^ ((drow & 7) << 3)];
        acc[0][dt] = __builtin_amdgcn_mfma_f32_16x16x32_bf16(bb, a0, acc[0][dt], 0, 0, 0);
        acc[1][dt] = __builtin_amdgcn_mfma_f32_16x16x32_bf16(bb, a1, acc[1][dt], 0, 0, 0);
      }
    }
    __syncthreads();
  }
  // epilogue: bf16 partial [s][b][256 d][256 c]
  size_t base = ((size_t)(s * NB + b)) << 16;
  #pragma unroll
  for (int i = 0; i < 2; i++) {
    int cc = w * 32 + i * 16 + lo;
    #pragma unroll
    for (int dt = 0; dt < 16; ++dt) {
      int dd = dt * 16 + hi * 4;
      #pragma unroll
      for (int r = 0; r < 4; r++)
        partial[base + (size_t)(dd + r) * 256 + cc] = f2bf(acc[i][dt][r]);
    }
  }
}

// ---------------- K2: elementwise reduce partials, scale 1/N, write kvT[d][c] bf16 ----------------
__global__ __launch_bounds__(256) void red_kernel(const u16* __restrict__ partial,
                                                  u16* __restrict__ kvT, int splits) {
  int j = blockIdx.x * 256 + threadIdx.x;   // 0..65535
  int b = j >> 13;
  int e0 = (j & 8191) * 8;
  size_t off = ((size_t)b << 16) + e0;
  const float inv = 1.0f / 4096.0f;
  float sum[8] = {0.f, 0.f, 0.f, 0.f, 0.f, 0.f, 0.f, 0.f};
  for (int s = 0; s < splits; ++s) {
    u16x8 p = *(const u16x8*)&partial[(((size_t)s * NB) << 16) + off];
    #pragma unroll
    for (int x = 0; x < 8; ++x) sum[x] += bf2f(p[x]);
  }
  u16x8 o;
  #pragma unroll
  for (int x = 0; x < 8; ++x) o[x] = f2bf(sum[x] * inv);
  *(u16x8*)&kvT[off] = o;
}

// ---------------- K3: out = normalize(q) @ kv, kv held in registers ----------------
// 512 threads = 8 waves; wave w owns d-tiles {2w, 2w+1} (32 out cols).
// Block grid-strides over 4 n-tiles of 16 rows each.
__global__ __launch_bounds__(512) void ctx_kernel(const float* __restrict__ query,
                                                  const u16* __restrict__ kvT,
                                                  float* __restrict__ out) {
  __shared__ __align__(16) u16 qn[16 * 256];  // 8 KB staged q-hat tile, XOR-swizzled
  int t = threadIdx.x;
  int b = blockIdx.y;
  int w = t >> 6, lane = t & 63, lo = lane & 15, hi = lane >> 4;
  const u16* kvb = kvT + ((size_t)b << 16);

  // prologue: load this wave's B-fragments once (its 32x256 slice of kv)
  short8 Bf[2][8];
  #pragma unroll
  for (int i = 0; i < 2; i++) {
    int dr = (2 * w + i) * 16 + lo;
    #pragma unroll
    for (int kc = 0; kc < 8; kc++)
      Bf[i][kc] = *(const short8*)&kvb[(size_t)dr * 256 + kc * 32 + 8 * hi];
  }

  int row = t >> 5, l32 = t & 31;  // staging role: 16 rows x 32 lanes x 8 floats
  for (int nt = 0; nt < 4; ++nt) {
    int n0 = (blockIdx.x * 4 + nt) * 16;
    // load + normalize one q row segment (32 B vectorized, coalesced)
    const float* qr = query + (size_t)(b * NN + n0 + row) * CDIM + l32 * 8;
    v4f x0 = *(const v4f*)qr;
    v4f x1 = *(const v4f*)(qr + 4);
    float ss = x0[0]*x0[0] + x0[1]*x0[1] + x0[2]*x0[2] + x0[3]*x0[3]
             + x1[0]*x1[0] + x1[1]*x1[1] + x1[2]*x1[2] + x1[3]*x1[3];
    #pragma unroll
    for (int m = 1; m < 32; m <<= 1) ss += __shfl_xor(ss, m);
    float sc = 1.0f / fmaxf(sqrtf(ss), 1e-12f);
    u16x8 qb;
    qb[0] = f2bf(x0[0] * sc); qb[1] = f2bf(x0[1] * sc);
    qb[2] = f2bf(x0[2] * sc); qb[3] = f2bf(x0[3] * sc);
    qb[4] = f2bf(x1[0] * sc); qb[5] = f2bf(x1[1] * sc);
    qb[6] = f2bf(x1[2] * sc); qb[7] = f2bf(x1[3] * sc);
    __syncthreads();  // previous tile's A-frag reads done before overwrite
    *(u16x8*)&qn[(row * 256 + l32 * 8) ^ ((row & 7) << 3)] = qb;
    __syncthreads();
    // A-fragments from LDS
    short8 Af[8];
    #pragma unroll
    for (int kc = 0; kc < 8; kc++)
      Af[kc] = *(const short8*)&qn[(lo * 256 + kc * 32 + 8 * hi) ^ ((lo & 7) << 3)];
    v4f acc0 = (v4f){0.f, 0.f, 0.f, 0.f};
    v4f acc1 = (v4f){0.f, 0.f, 0.f, 0.f};
    #pragma unroll
    for (int kc = 0; kc < 8; kc++) {
      acc0 = __builtin_amdgcn_mfma_f32_16x16x32_bf16(Af[kc], Bf[0][kc], acc0, 0, 0, 0);
      acc1 = __builtin_amdgcn_mfma_f32_16x16x32_bf16(Af[kc], Bf[1][kc], acc1, 0, 0, 0);
    }
    // store 16x32 slice: row = n0 + 4*hi + r, col = (2w+i)*16 + lo
    #pragma unroll
    for (int r = 0; r < 4; r++) {
      size_t ro = (size_t)(b * NN + n0 + 4 * hi + r) * CDIM;
      out[ro + (2 * w) * 16 + lo] = acc0[r];
      out[ro + (2 * w + 1) * 16 + lo] = acc1[r];
    }
  }
}

extern "C" void kernel_launch(void* const* d_in, const int* in_sizes, int n_in,
                              void* d_out, int out_size, void* d_ws, size_t ws_size,
                              hipStream_t stream) {
  const float* q = (const float*)d_in[0];
  const float* k = (const float*)d_in[1];
  const float* v = (const float*)d_in[2];
  float* out = (float*)d_out;

  // ws layout: [s_k: 32768 f32][partial: splits*8*256*256 bf16][kvT: 8*256*256 bf16]
  int splits = 32;
  while (splits > 2) {
    size_t need = 131072ull + ((size_t)splits + 1ull) * 1048576ull;
    if (need <= ws_size) break;
    splits >>= 1;
  }
  float* s_k = (float*)d_ws;
  u16* partial = (u16*)((char*)d_ws + 131072);
  u16* kvT = (u16*)((char*)d_ws + 131072 + (size_t)splits * 1048576ull);

  knorm_kernel<<<dim3(8192), dim3(256), 0, stream>>>(k, s_k);
  kv_kernel<<<dim3(splits, NB), dim3(512), 0, stream>>>(k, v, s_k, partial, MM / splits);
  red_kernel<<<dim3(256), dim3(256), 0, stream>>>(partial, kvT, splits);
  ctx_kernel<<<dim3(64, NB), dim3(512), 0, stream>>>(q, kvT, out);
}